// Round 8
// baseline (304.597 us; speedup 1.0000x reference)
//
#include <hip/hip_runtime.h>
#include <hip/hip_bf16.h>

#define N_NODES 100000
#define N_EDGES 800000
#define D 64
#define SCAN_B 256
#define NB1 ((N_NODES + SCAN_B - 1) / SCAN_B)   // 391 blocks
#define FILL_BLOCKS (N_EDGES / 256)             // 3125, exact
#define INIT_BLOCKS (N_NODES * D / 256)         // 25000, exact

// bf16 helpers: storage-only bf16 (embeds); all math in fp32.
__device__ __forceinline__ unsigned short f2bf(float f) {
    union { float f; unsigned u; } v; v.f = f;
    unsigned r = v.u + 0x7fffu + ((v.u >> 16) & 1u);   // round-to-nearest-even
    return (unsigned short)(r >> 16);
}
__device__ __forceinline__ void acc_bf8(float acc[8], uint4 u) {
    acc[0] += __uint_as_float(u.x << 16);
    acc[1] += __uint_as_float(u.x & 0xffff0000u);
    acc[2] += __uint_as_float(u.y << 16);
    acc[3] += __uint_as_float(u.y & 0xffff0000u);
    acc[4] += __uint_as_float(u.z << 16);
    acc[5] += __uint_as_float(u.z & 0xffff0000u);
    acc[6] += __uint_as_float(u.w << 16);
    acc[7] += __uint_as_float(u.w & 0xffff0000u);
}
// Pin a float4's components into VGPRs: empty asm whose outputs are opaque —
// the compiler cannot rematerialize them by re-loading from memory. (A plain
// load of const __restrict__ W is legally re-loadable, and the allocator's
// occupancy heuristic chose to sink the 16-KB W re-load into the chunk loop:
// VGPR_Count 48, ~1.6 GB of L1/L2 re-reads, 49 us. This forces residency.)
__device__ __forceinline__ void pin4(float4& v) {
    asm volatile("" : "+v"(v.x), "+v"(v.y), "+v"(v.z), "+v"(v.w));
}

// ---------------------------------------------------------------------------
// hist + rank: deg[dst]++, rank[e] = arrival order of edge e at its dst.
__global__ __launch_bounds__(256) void hist_rank_kernel(
        const int2* __restrict__ edges,
        int* __restrict__ deg,
        int* __restrict__ rank) {
    int t = blockIdx.x * 256 + threadIdx.x;
    int2 e = edges[t];                      // grid exact: 3125*256 == N_EDGES
    rank[t] = atomicAdd(&deg[e.y], 1);
}

// ---------------------------------------------------------------------------
// Scans (exclusive prefix over deg -> row_ptr)
__global__ void scan1_kernel(const int* __restrict__ deg,
                             int* __restrict__ row_ptr,
                             int* __restrict__ bsum) {
    __shared__ int tmp[SCAN_B];
    int t = threadIdx.x;
    int i = blockIdx.x * SCAN_B + t;
    int v = (i < N_NODES) ? deg[i] : 0;
    tmp[t] = v;
    __syncthreads();
#pragma unroll
    for (int off = 1; off < SCAN_B; off <<= 1) {
        int a = (t >= off) ? tmp[t - off] : 0;
        __syncthreads();
        tmp[t] += a;
        __syncthreads();
    }
    if (i < N_NODES) row_ptr[i] = tmp[t] - v;   // exclusive
    if (t == SCAN_B - 1) bsum[blockIdx.x] = tmp[t];
}

__global__ void scan2_kernel(const int* __restrict__ bsum, int* __restrict__ boff) {
    __shared__ int tmp[512];
    int t = threadIdx.x;
    int v = (t < NB1) ? bsum[t] : 0;
    tmp[t] = v;
    __syncthreads();
#pragma unroll
    for (int off = 1; off < 512; off <<= 1) {
        int a = (t >= off) ? tmp[t - off] : 0;
        __syncthreads();
        tmp[t] += a;
        __syncthreads();
    }
    if (t < NB1) boff[t] = tmp[t] - v;
}

__global__ void scan3_kernel(int* __restrict__ row_ptr,
                             const int* __restrict__ boff) {
    int i = blockIdx.x * SCAN_B + threadIdx.x;
    if (i < N_NODES) row_ptr[i] += boff[i >> 8];
    if (i == 0) row_ptr[N_NODES] = N_EDGES;
}

// ---------------------------------------------------------------------------
// Fused dispatch: blocks [0, FILL_BLOCKS) scatter CSR cols (atomic-free via
// rank); blocks [FILL_BLOCKS, +INIT_BLOCKS) compute initial embeddings (bf16).
__global__ __launch_bounds__(256) void fill_init_kernel(
        const int2* __restrict__ edges,
        const int* __restrict__ rank,
        const int* __restrict__ rowp,
        int* __restrict__ col,
        const int* __restrict__ nodes,
        const float* __restrict__ features,
        const float* __restrict__ node_emb,
        const float* __restrict__ feat_W,
        const float* __restrict__ feat_b,
        unsigned short* __restrict__ embeds) {
    if (blockIdx.x < FILL_BLOCKS) {
        int t = blockIdx.x * 256 + threadIdx.x;
        int2 e = edges[t];
        col[rowp[e.y] + rank[t]] = e.x;
    } else {
        int tid = (blockIdx.x - FILL_BLOCKS) * 256 + threadIdx.x;
        int node = tid >> 6;
        int d = tid & 63;
        float acc = feat_b[d];
        const float* f = features + (size_t)node * 10;
        const float* w = feat_W + (size_t)d * 10;
#pragma unroll
        for (int j = 0; j < 10; ++j) acc += f[j] * w[j];
        embeds[tid] = f2bf(node_emb[(size_t)nodes[node] * D + d] + acc);
    }
}

// ---------------------------------------------------------------------------
// x[node] = emb_in[node] + sum_{src} emb_in[src]   (emb bf16, acc fp32)
// One WAVE per node (uniform trips). 8 groups x 8 lanes: group g loads the
// row of src (r*8+g) as uint4 (8 bf16 = 16 B/lane, 128 B/row coalesced).
// 32-edge chunks, 4 static rounds: 8 independent rows in flight per wave.
__global__ __launch_bounds__(256, 6) void gather_x_kernel(
        const unsigned short* __restrict__ emb_in,
        const int* __restrict__ rowp,
        const int* __restrict__ col,
        float* __restrict__ x_out) {
    int lane = threadIdx.x & 63;
    int wv   = threadIdx.x >> 6;
    int node = blockIdx.x * 4 + wv;          // grid = 25000, exact
    int g = lane >> 3;                        // row-group 0..7
    int c = lane & 7;                         // uint4 chunk 0..7

    int start = rowp[node];
    int end   = rowp[node + 1];

    float acc[8];
#pragma unroll
    for (int j = 0; j < 8; ++j) acc[j] = 0.f;
    if (g == 0) {                             // self term, counted once
        uint4 u = ((const uint4*)(emb_in + (size_t)node * D))[c];
        acc_bf8(acc, u);
    }

    for (int base = start; base < end; base += 32) {
        int nb = end - base; if (nb > 32) nb = 32;
        int idx = (lane < nb) ? col[base + lane] : 0;   // lanes 0..31, coalesced
#pragma unroll
        for (int r = 0; r < 4; ++r) {
            int s = r * 8 + g;                          // 0..31
            int src = __shfl(idx, s, 64);               // all lanes active
            if (s < nb) {                               // per-lane predication
                uint4 u = ((const uint4*)(emb_in + (size_t)src * D))[c];
                acc_bf8(acc, u);
            }
        }
    }

    // combine the 8 group partials (xor 8, 16, 32)
#pragma unroll
    for (int m = 8; m <= 32; m <<= 1) {
#pragma unroll
        for (int j = 0; j < 8; ++j) acc[j] += __shfl_xor(acc[j], m, 64);
    }

    if (g == 0) {                             // 8 lanes x 32 B = 256 B fp32 row
        float4 a0 = make_float4(acc[0], acc[1], acc[2], acc[3]);
        float4 a1 = make_float4(acc[4], acc[5], acc[6], acc[7]);
        float4* o = (float4*)(x_out + (size_t)node * D);
        o[2 * c]     = a0;
        o[2 * c + 1] = a1;
    }
}

// ---------------------------------------------------------------------------
// y = relu(x @ W^T + b); !SCORE: store bf16 embeds; SCORE: cosine-vs-pattern.
// Grid-stride over 4-node chunks; wave wv owns node chunk*4+wv; lane = out dim.
// W row lives in VGPRs, PINNED via empty asm so the allocator cannot sink the
// (legally re-loadable) const loads back into the loop. launch_bounds(256,4)
// gives a 128-VGPR budget. xs[wv] is wave-private: LDS ops are in-order per
// wave, compiler inserts lgkmcnt waits -- no barrier needed.
// 2-stage prefetch: next chunk's x load overlaps current chunk's FMAs.
template <bool SCORE>
__global__ __launch_bounds__(256, 4) void conv_kernel(
        const float* __restrict__ x,
        const float* __restrict__ W,
        const float* __restrict__ b,
        const float* __restrict__ pattern_emb,
        const int* __restrict__ pattern_id,
        unsigned short* __restrict__ emb_out,
        float* __restrict__ score_out) {
    __shared__ float4 xs[4][16];

    int lane = threadIdx.x & 63;
    int wv   = threadIdx.x >> 6;
    float bias = b[lane];

    float4 Wr[16];
    const float4* W4 = (const float4*)(W + (size_t)lane * D);
#pragma unroll
    for (int k = 0; k < 16; ++k) Wr[k] = W4[k];
#pragma unroll
    for (int k = 0; k < 16; ++k) pin4(Wr[k]);   // opaque -> must stay resident

    float p = 0.f, pnorm = 1.f;
    if (SCORE) {
        p = pattern_emb[(size_t)pattern_id[0] * D + lane];
        float pn = p * p;
#pragma unroll
        for (int m = 32; m > 0; m >>= 1) pn += __shfl_xor(pn, m, 64);
        pnorm = fmaxf(sqrtf(pn), 1e-8f);
    }

    const int n_chunks = N_NODES / 4;         // 25000, exact
    int chunk = blockIdx.x;
    float4 xreg = make_float4(0.f, 0.f, 0.f, 0.f);
    if (chunk < n_chunks && lane < 16)
        xreg = ((const float4*)(x + (size_t)(chunk * 4 + wv) * D))[lane];

    for (; chunk < n_chunks; chunk += gridDim.x) {
        int node = chunk * 4 + wv;
        if (lane < 16) xs[wv][lane] = xreg;   // ds_write; reads below auto-wait
        int nchunk = chunk + gridDim.x;       // prefetch next chunk's x
        if (nchunk < n_chunks && lane < 16)
            xreg = ((const float4*)(x + (size_t)(nchunk * 4 + wv) * D))[lane];

        float y = bias;
#pragma unroll
        for (int k = 0; k < 16; ++k) {
            float4 x4 = xs[wv][k];            // wave-broadcast ds_read_b128
            y += Wr[k].x * x4.x + Wr[k].y * x4.y + Wr[k].z * x4.z + Wr[k].w * x4.w;
        }
        y = fmaxf(y, 0.0f);
        if (!SCORE) {
            emb_out[(size_t)node * D + lane] = f2bf(y);
        } else {
            float dot = y * p;
            float n2  = y * y;
#pragma unroll
            for (int m = 32; m > 0; m >>= 1) {
                dot += __shfl_xor(dot, m, 64);
                n2  += __shfl_xor(n2, m, 64);
            }
            if (lane == 0)
                score_out[node] = dot / (fmaxf(sqrtf(n2), 1e-8f) * pnorm);
        }
    }
}

// ---------------------------------------------------------------------------
// Fallback path (atomic scatter, full fp32) if ws too small for CSR arrays.
__global__ void init_embeds_kernel(const int* __restrict__ nodes,
                                   const float* __restrict__ features,
                                   const float* __restrict__ node_emb,
                                   const float* __restrict__ feat_W,
                                   const float* __restrict__ feat_b,
                                   float* __restrict__ embeds) {
    int tid = blockIdx.x * blockDim.x + threadIdx.x;
    if (tid >= N_NODES * D) return;
    int node = tid >> 6;
    int d = tid & 63;
    float acc = feat_b[d];
    const float* f = features + (size_t)node * 10;
    const float* w = feat_W + (size_t)d * 10;
#pragma unroll
    for (int j = 0; j < 10; ++j) acc += f[j] * w[j];
    embeds[tid] = node_emb[(size_t)nodes[node] * D + d] + acc;
}

__global__ void scatter_add_kernel(const int* __restrict__ edges,
                                   const float* __restrict__ embeds,
                                   float* __restrict__ agg) {
    int tid = blockIdx.x * blockDim.x + threadIdx.x;
    int edge = tid >> 6;
    int lane = tid & 63;
    if (edge >= N_EDGES) return;
    int src = edges[2 * edge + 0];
    int dst = edges[2 * edge + 1];
    atomicAdd(&agg[(size_t)dst * D + lane], embeds[(size_t)src * D + lane]);
}

__global__ void conv_inplace_kernel(const float* __restrict__ agg,
                                    const float* __restrict__ W,
                                    const float* __restrict__ b,
                                    float* __restrict__ embeds) {
    __shared__ float Ws[D * 65];
    __shared__ float xs[4][D];
    for (int i = threadIdx.x; i < D * D; i += blockDim.x) {
        int d = i >> 6, k = i & 63;
        Ws[d * 65 + k] = W[i];
    }
    __syncthreads();
    int lane_d = threadIdx.x & 63;
    int local_n = threadIdx.x >> 6;
    float bias = b[lane_d];
    const int n_chunks = (N_NODES + 3) / 4;
    for (int chunk = blockIdx.x; chunk < n_chunks; chunk += gridDim.x) {
        int node = chunk * 4 + local_n;
        if (node < N_NODES) {
            size_t base = (size_t)node * D + lane_d;
            xs[local_n][lane_d] = embeds[base] + agg[base];
        }
        __syncthreads();
        if (node < N_NODES) {
            float acc = bias;
#pragma unroll
            for (int k = 0; k < D; ++k) acc += xs[local_n][k] * Ws[lane_d * 65 + k];
            embeds[(size_t)node * D + lane_d] = fmaxf(acc, 0.0f);
        }
        __syncthreads();
    }
}

__global__ void final_score_kernel(const float* __restrict__ embeds,
                                   const float* __restrict__ pattern_emb,
                                   const int* __restrict__ pattern_id,
                                   float* __restrict__ out) {
    int lane = threadIdx.x & 63;
    int wave = threadIdx.x >> 6;
    int node = blockIdx.x * 4 + wave;
    int pid = pattern_id[0];
    float p = pattern_emb[(size_t)pid * D + lane];
    float pn = p * p;
#pragma unroll
    for (int m = 32; m > 0; m >>= 1) pn += __shfl_xor(pn, m, 64);
    if (node < N_NODES) {
        float e = embeds[(size_t)node * D + lane];
        float dot = e * p;
        float n2 = e * e;
#pragma unroll
        for (int m = 32; m > 0; m >>= 1) {
            dot += __shfl_xor(dot, m, 64);
            n2  += __shfl_xor(n2, m, 64);
        }
        if (lane == 0) {
            float denom = fmaxf(sqrtf(n2), 1e-8f) * fmaxf(sqrtf(pn), 1e-8f);
            out[node] = dot / denom;
        }
    }
}

// ---------------------------------------------------------------------------
extern "C" void kernel_launch(void* const* d_in, const int* in_sizes, int n_in,
                              void* d_out, int out_size, void* d_ws, size_t ws_size,
                              hipStream_t stream) {
    const int*   nodes       = (const int*)d_in[0];
    const int*   edges       = (const int*)d_in[1];
    const float* features    = (const float*)d_in[2];
    const float* node_emb    = (const float*)d_in[3];
    const float* feat_W      = (const float*)d_in[4];
    const float* feat_b      = (const float*)d_in[5];
    const float* conv1_W     = (const float*)d_in[6];
    const float* conv1_b     = (const float*)d_in[7];
    const float* pattern_emb = (const float*)d_in[8];
    const int*   pattern_id  = (const int*)d_in[9];
    float* out = (float*)d_out;

    const size_t emb_f32_bytes = (size_t)N_NODES * D * sizeof(float);   // 25.6 MB
    const size_t emb_bf_bytes  = (size_t)N_NODES * D * 2;               // 12.8 MB
    auto align256 = [](size_t x) { return (x + 255) & ~(size_t)255; };

    size_t o_embA = 0;
    size_t o_embB = o_embA + align256(emb_bf_bytes);
    size_t o_xbuf = o_embB + align256(emb_bf_bytes);
    size_t o_col  = o_xbuf + align256(emb_f32_bytes);
    size_t o_rank = o_col  + align256((size_t)N_EDGES * 4);
    size_t o_row  = o_rank + align256((size_t)N_EDGES * 4);
    size_t o_deg  = o_row  + align256((size_t)(N_NODES + 1) * 4);
    size_t o_bsum = o_deg  + align256((size_t)N_NODES * 4);
    size_t o_boff = o_bsum + align256((size_t)NB1 * 4);
    size_t need   = o_boff + align256((size_t)NB1 * 4);

    char* ws = (char*)d_ws;

    if (ws_size >= need) {
        unsigned short* embA = (unsigned short*)(ws + o_embA);
        unsigned short* embB = (unsigned short*)(ws + o_embB);
        float* xbuf = (float*)(ws + o_xbuf);
        int*   col  = (int*)(ws + o_col);
        int*   rank = (int*)(ws + o_rank);
        int*   rowp = (int*)(ws + o_row);
        int*   deg  = (int*)(ws + o_deg);
        int*   bsum = (int*)(ws + o_bsum);
        int*   boff = (int*)(ws + o_boff);

        hipMemsetAsync(deg, 0, (size_t)N_NODES * 4, stream);
        hist_rank_kernel<<<FILL_BLOCKS, 256, 0, stream>>>((const int2*)edges, deg, rank);
        scan1_kernel<<<NB1, SCAN_B, 0, stream>>>(deg, rowp, bsum);
        scan2_kernel<<<1, 512, 0, stream>>>(bsum, boff);
        scan3_kernel<<<NB1, SCAN_B, 0, stream>>>(rowp, boff);
        fill_init_kernel<<<FILL_BLOCKS + INIT_BLOCKS, 256, 0, stream>>>(
            (const int2*)edges, rank, rowp, col,
            nodes, features, node_emb, feat_W, feat_b, embA);

        // iter 1: gather(bf16->fp32) + conv -> embB (bf16)
        gather_x_kernel<<<N_NODES / 4, 256, 0, stream>>>(embA, rowp, col, xbuf);
        conv_kernel<false><<<2048, 256, 0, stream>>>(
            xbuf, conv1_W, conv1_b, pattern_emb, pattern_id, embB, nullptr);
        // iter 2: gather + conv fused with cosine score -> out
        gather_x_kernel<<<N_NODES / 4, 256, 0, stream>>>(embB, rowp, col, xbuf);
        conv_kernel<true><<<2048, 256, 0, stream>>>(
            xbuf, conv1_W, conv1_b, pattern_emb, pattern_id, nullptr, out);
    } else {
        float* embeds = (float*)ws;
        float* agg = (float*)(ws + align256(emb_f32_bytes));
        init_embeds_kernel<<<(N_NODES * D + 255) / 256, 256, 0, stream>>>(
            nodes, features, node_emb, feat_W, feat_b, embeds);
        for (int it = 0; it < 2; ++it) {
            hipMemsetAsync(agg, 0, emb_f32_bytes, stream);
            long long total = (long long)N_EDGES * 64;
            scatter_add_kernel<<<(int)((total + 255) / 256), 256, 0, stream>>>(edges, embeds, agg);
            conv_inplace_kernel<<<2048, 256, 0, stream>>>(agg, conv1_W, conv1_b, embeds);
        }
        final_score_kernel<<<(N_NODES + 3) / 4, 256, 0, stream>>>(
            embeds, pattern_emb, pattern_id, out);
    }
}

// Round 9
// 259.662 us; speedup vs baseline: 1.1731x; 1.1731x over previous
//
#include <hip/hip_runtime.h>
#include <hip/hip_bf16.h>

#define N_NODES 100000
#define N_EDGES 800000
#define D 64
#define SCAN_B 256
#define NB1 ((N_NODES + SCAN_B - 1) / SCAN_B)   // 391 blocks
#define FILL_BLOCKS (N_EDGES / 256)             // 3125, exact
#define INIT_BLOCKS (N_NODES * D / 256)         // 25000, exact
#define CT 64                                   // conv tile: nodes per block
#define XS 68                                   // fp32 LDS row stride (bank-safe)
#define OS 72                                   // u16 LDS out row stride

// bf16 helpers: storage-only bf16 (embeds); all math in fp32.
__device__ __forceinline__ unsigned short f2bf(float f) {
    union { float f; unsigned u; } v; v.f = f;
    unsigned r = v.u + 0x7fffu + ((v.u >> 16) & 1u);   // round-to-nearest-even
    return (unsigned short)(r >> 16);
}
__device__ __forceinline__ void acc_bf8(float acc[8], uint4 u) {
    acc[0] += __uint_as_float(u.x << 16);
    acc[1] += __uint_as_float(u.x & 0xffff0000u);
    acc[2] += __uint_as_float(u.y << 16);
    acc[3] += __uint_as_float(u.y & 0xffff0000u);
    acc[4] += __uint_as_float(u.z << 16);
    acc[5] += __uint_as_float(u.z & 0xffff0000u);
    acc[6] += __uint_as_float(u.w << 16);
    acc[7] += __uint_as_float(u.w & 0xffff0000u);
}

// ---------------------------------------------------------------------------
// hist + rank: deg[dst]++, rank[e] = arrival order of edge e at its dst.
__global__ __launch_bounds__(256) void hist_rank_kernel(
        const int2* __restrict__ edges,
        int* __restrict__ deg,
        int* __restrict__ rank) {
    int t = blockIdx.x * 256 + threadIdx.x;
    int2 e = edges[t];                      // grid exact: 3125*256 == N_EDGES
    rank[t] = atomicAdd(&deg[e.y], 1);
}

// ---------------------------------------------------------------------------
// Scans (exclusive prefix over deg -> row_ptr)
__global__ void scan1_kernel(const int* __restrict__ deg,
                             int* __restrict__ row_ptr,
                             int* __restrict__ bsum) {
    __shared__ int tmp[SCAN_B];
    int t = threadIdx.x;
    int i = blockIdx.x * SCAN_B + t;
    int v = (i < N_NODES) ? deg[i] : 0;
    tmp[t] = v;
    __syncthreads();
#pragma unroll
    for (int off = 1; off < SCAN_B; off <<= 1) {
        int a = (t >= off) ? tmp[t - off] : 0;
        __syncthreads();
        tmp[t] += a;
        __syncthreads();
    }
    if (i < N_NODES) row_ptr[i] = tmp[t] - v;   // exclusive
    if (t == SCAN_B - 1) bsum[blockIdx.x] = tmp[t];
}

__global__ void scan2_kernel(const int* __restrict__ bsum, int* __restrict__ boff) {
    __shared__ int tmp[512];
    int t = threadIdx.x;
    int v = (t < NB1) ? bsum[t] : 0;
    tmp[t] = v;
    __syncthreads();
#pragma unroll
    for (int off = 1; off < 512; off <<= 1) {
        int a = (t >= off) ? tmp[t - off] : 0;
        __syncthreads();
        tmp[t] += a;
        __syncthreads();
    }
    if (t < NB1) boff[t] = tmp[t] - v;
}

__global__ void scan3_kernel(int* __restrict__ row_ptr,
                             const int* __restrict__ boff) {
    int i = blockIdx.x * SCAN_B + threadIdx.x;
    if (i < N_NODES) row_ptr[i] += boff[i >> 8];
    if (i == 0) row_ptr[N_NODES] = N_EDGES;
}

// ---------------------------------------------------------------------------
// Fused dispatch: blocks [0, FILL_BLOCKS) scatter CSR cols (atomic-free via
// rank); blocks [FILL_BLOCKS, +INIT_BLOCKS) compute initial embeddings (bf16).
__global__ __launch_bounds__(256) void fill_init_kernel(
        const int2* __restrict__ edges,
        const int* __restrict__ rank,
        const int* __restrict__ rowp,
        int* __restrict__ col,
        const int* __restrict__ nodes,
        const float* __restrict__ features,
        const float* __restrict__ node_emb,
        const float* __restrict__ feat_W,
        const float* __restrict__ feat_b,
        unsigned short* __restrict__ embeds) {
    if (blockIdx.x < FILL_BLOCKS) {
        int t = blockIdx.x * 256 + threadIdx.x;
        int2 e = edges[t];
        col[rowp[e.y] + rank[t]] = e.x;
    } else {
        int tid = (blockIdx.x - FILL_BLOCKS) * 256 + threadIdx.x;
        int node = tid >> 6;
        int d = tid & 63;
        float acc = feat_b[d];
        const float* f = features + (size_t)node * 10;
        const float* w = feat_W + (size_t)d * 10;
#pragma unroll
        for (int j = 0; j < 10; ++j) acc += f[j] * w[j];
        embeds[tid] = f2bf(node_emb[(size_t)nodes[node] * D + d] + acc);
    }
}

// ---------------------------------------------------------------------------
// x[node] = emb_in[node] + sum_{src} emb_in[src]   (emb bf16, acc fp32)
// One WAVE per node (uniform trips). 8 groups x 8 lanes: group g loads the
// row of src (r*8+g) as uint4 (8 bf16 = 16 B/lane, 128 B/row coalesced).
// 32-edge chunks, 4 static rounds: 8 independent rows in flight per wave.
__global__ __launch_bounds__(256, 6) void gather_x_kernel(
        const unsigned short* __restrict__ emb_in,
        const int* __restrict__ rowp,
        const int* __restrict__ col,
        float* __restrict__ x_out) {
    int lane = threadIdx.x & 63;
    int wv   = threadIdx.x >> 6;
    int node = blockIdx.x * 4 + wv;          // grid = 25000, exact
    int g = lane >> 3;                        // row-group 0..7
    int c = lane & 7;                         // uint4 chunk 0..7

    int start = rowp[node];
    int end   = rowp[node + 1];

    float acc[8];
#pragma unroll
    for (int j = 0; j < 8; ++j) acc[j] = 0.f;
    if (g == 0) {                             // self term, counted once
        uint4 u = ((const uint4*)(emb_in + (size_t)node * D))[c];
        acc_bf8(acc, u);
    }

    for (int base = start; base < end; base += 32) {
        int nb = end - base; if (nb > 32) nb = 32;
        int idx = (lane < nb) ? col[base + lane] : 0;   // lanes 0..31, coalesced
#pragma unroll
        for (int r = 0; r < 4; ++r) {
            int s = r * 8 + g;                          // 0..31
            int src = __shfl(idx, s, 64);               // all lanes active
            if (s < nb) {                               // per-lane predication
                uint4 u = ((const uint4*)(emb_in + (size_t)src * D))[c];
                acc_bf8(acc, u);
            }
        }
    }

    // combine the 8 group partials (xor 8, 16, 32)
#pragma unroll
    for (int m = 8; m <= 32; m <<= 1) {
#pragma unroll
        for (int j = 0; j < 8; ++j) acc[j] += __shfl_xor(acc[j], m, 64);
    }

    if (g == 0) {                             // 8 lanes x 32 B = 256 B fp32 row
        float4 a0 = make_float4(acc[0], acc[1], acc[2], acc[3]);
        float4 a1 = make_float4(acc[4], acc[5], acc[6], acc[7]);
        float4* o = (float4*)(x_out + (size_t)node * D);
        o[2 * c]     = a0;
        o[2 * c + 1] = a1;
    }
}

// ---------------------------------------------------------------------------
// Tiled conv GEMM: y = relu(x @ W^T + b) for a 64-node tile.
// X-tile and W both staged in LDS (stride 68 floats -> all inner-loop b128
// reads are <=2-way bank aliased = free). Thread (i=t&15, j=t>>4) computes a
// STRIDED 4x4 microtile: nodes i+16di, dims j+16dj. No W-in-VGPR residency
// needed (the round-2/6/7/8 allocator battles are structurally avoided).
// !SCORE: emit bf16 embeds (via LDS transpose for coalescing).
// SCORE: reuse Xs for fp32 y, per-node in-LDS dot vs pattern -> score_out.
template <bool SCORE>
__global__ __launch_bounds__(256) void conv_tile_kernel(
        const float* __restrict__ x,
        const float* __restrict__ W,
        const float* __restrict__ b,
        const float* __restrict__ pattern_emb,
        const int* __restrict__ pattern_id,
        unsigned short* __restrict__ emb_out,
        float* __restrict__ score_out) {
    __shared__ float Xs[CT][XS];
    __shared__ float Wsh[D][XS];
    __shared__ unsigned short Os[CT][OS];
    __shared__ float ps[D];

    int t = threadIdx.x;
    int base = blockIdx.x * CT;
    int i = t & 15;           // node sub-index
    int j = t >> 4;           // dim sub-index

    // bias for this thread's 4 output dims (j+16dj)
    float bj[4];
#pragma unroll
    for (int dj = 0; dj < 4; ++dj) bj[dj] = b[j + 16 * dj];

    // stage W (16 KB) and X tile (16 KB): row = t>>4 (+16 per pass), chunk = t&15
    {
        int c = t & 15;
        int r0 = t >> 4;
#pragma unroll
        for (int p4 = 0; p4 < 4; ++p4) {
            int r = r0 + p4 * 16;
            float4 wv4 = ((const float4*)(W + (size_t)r * D))[c];
            *((float4*)&Wsh[r][4 * c]) = wv4;
            int node = base + r;
            int nc = node < N_NODES ? node : (N_NODES - 1);
            float4 xv4 = ((const float4*)(x + (size_t)nc * D))[c];
            *((float4*)&Xs[r][4 * c]) = xv4;
        }
    }
    if (SCORE && t < D) ps[t] = pattern_emb[(size_t)pattern_id[0] * D + t];
    __syncthreads();

    float acc[4][4] = {};
    for (int k4 = 0; k4 < 16; ++k4) {
        float4 xr[4], wr[4];
#pragma unroll
        for (int di = 0; di < 4; ++di) xr[di] = *((const float4*)&Xs[i + 16 * di][4 * k4]);
#pragma unroll
        for (int dj = 0; dj < 4; ++dj) wr[dj] = *((const float4*)&Wsh[j + 16 * dj][4 * k4]);
#pragma unroll
        for (int di = 0; di < 4; ++di)
#pragma unroll
            for (int dj = 0; dj < 4; ++dj)
                acc[di][dj] += xr[di].x * wr[dj].x + xr[di].y * wr[dj].y
                             + xr[di].z * wr[dj].z + xr[di].w * wr[dj].w;
    }

    if (!SCORE) {
        // bf16 via LDS transpose for coalesced 128-B row writes
#pragma unroll
        for (int di = 0; di < 4; ++di)
#pragma unroll
            for (int dj = 0; dj < 4; ++dj)
                Os[i + 16 * di][j + 16 * dj] = f2bf(fmaxf(acc[di][dj] + bj[dj], 0.f));
        __syncthreads();
#pragma unroll
        for (int q = 0; q < 2; ++q) {
            int idx = t + q * 256;            // 0..511: 64 rows x 8 uint4 segs
            int r = idx >> 3, seg = idx & 7;
            int node = base + r;
            if (node < N_NODES)
                ((uint4*)(emb_out + (size_t)node * D))[seg] = *((const uint4*)&Os[r][8 * seg]);
        }
    } else {
        __syncthreads();                       // all waves done reading Xs
#pragma unroll
        for (int di = 0; di < 4; ++di)
#pragma unroll
            for (int dj = 0; dj < 4; ++dj)
                Xs[i + 16 * di][j + 16 * dj] = fmaxf(acc[di][dj] + bj[dj], 0.f);
        __syncthreads();
        if (t < CT) {                          // wave 0: one lane per node
            float dot = 0.f, n2 = 0.f, pn = 0.f;
#pragma unroll 8
            for (int k = 0; k < D; ++k) {
                float yk = Xs[t][k];
                float pk = ps[k];              // uniform -> broadcast, free
                dot += yk * pk; n2 += yk * yk; pn += pk * pk;
            }
            int node = base + t;
            if (node < N_NODES)
                score_out[node] = dot / (fmaxf(sqrtf(n2), 1e-8f) * fmaxf(sqrtf(pn), 1e-8f));
        }
    }
}

// ---------------------------------------------------------------------------
// Fallback path (atomic scatter, full fp32) if ws too small for CSR arrays.
__global__ void init_embeds_kernel(const int* __restrict__ nodes,
                                   const float* __restrict__ features,
                                   const float* __restrict__ node_emb,
                                   const float* __restrict__ feat_W,
                                   const float* __restrict__ feat_b,
                                   float* __restrict__ embeds) {
    int tid = blockIdx.x * blockDim.x + threadIdx.x;
    if (tid >= N_NODES * D) return;
    int node = tid >> 6;
    int d = tid & 63;
    float acc = feat_b[d];
    const float* f = features + (size_t)node * 10;
    const float* w = feat_W + (size_t)d * 10;
#pragma unroll
    for (int j = 0; j < 10; ++j) acc += f[j] * w[j];
    embeds[tid] = node_emb[(size_t)nodes[node] * D + d] + acc;
}

__global__ void scatter_add_kernel(const int* __restrict__ edges,
                                   const float* __restrict__ embeds,
                                   float* __restrict__ agg) {
    int tid = blockIdx.x * blockDim.x + threadIdx.x;
    int edge = tid >> 6;
    int lane = tid & 63;
    if (edge >= N_EDGES) return;
    int src = edges[2 * edge + 0];
    int dst = edges[2 * edge + 1];
    atomicAdd(&agg[(size_t)dst * D + lane], embeds[(size_t)src * D + lane]);
}

__global__ void conv_inplace_kernel(const float* __restrict__ agg,
                                    const float* __restrict__ W,
                                    const float* __restrict__ b,
                                    float* __restrict__ embeds) {
    __shared__ float Ws[D * 65];
    __shared__ float xs[4][D];
    for (int i = threadIdx.x; i < D * D; i += blockDim.x) {
        int d = i >> 6, k = i & 63;
        Ws[d * 65 + k] = W[i];
    }
    __syncthreads();
    int lane_d = threadIdx.x & 63;
    int local_n = threadIdx.x >> 6;
    float bias = b[lane_d];
    const int n_chunks = (N_NODES + 3) / 4;
    for (int chunk = blockIdx.x; chunk < n_chunks; chunk += gridDim.x) {
        int node = chunk * 4 + local_n;
        if (node < N_NODES) {
            size_t base = (size_t)node * D + lane_d;
            xs[local_n][lane_d] = embeds[base] + agg[base];
        }
        __syncthreads();
        if (node < N_NODES) {
            float acc = bias;
#pragma unroll
            for (int k = 0; k < D; ++k) acc += xs[local_n][k] * Ws[lane_d * 65 + k];
            embeds[(size_t)node * D + lane_d] = fmaxf(acc, 0.0f);
        }
        __syncthreads();
    }
}

__global__ void final_score_kernel(const float* __restrict__ embeds,
                                   const float* __restrict__ pattern_emb,
                                   const int* __restrict__ pattern_id,
                                   float* __restrict__ out) {
    int lane = threadIdx.x & 63;
    int wave = threadIdx.x >> 6;
    int node = blockIdx.x * 4 + wave;
    int pid = pattern_id[0];
    float p = pattern_emb[(size_t)pid * D + lane];
    float pn = p * p;
#pragma unroll
    for (int m = 32; m > 0; m >>= 1) pn += __shfl_xor(pn, m, 64);
    if (node < N_NODES) {
        float e = embeds[(size_t)node * D + lane];
        float dot = e * p;
        float n2 = e * e;
#pragma unroll
        for (int m = 32; m > 0; m >>= 1) {
            dot += __shfl_xor(dot, m, 64);
            n2  += __shfl_xor(n2, m, 64);
        }
        if (lane == 0) {
            float denom = fmaxf(sqrtf(n2), 1e-8f) * fmaxf(sqrtf(pn), 1e-8f);
            out[node] = dot / denom;
        }
    }
}

// ---------------------------------------------------------------------------
extern "C" void kernel_launch(void* const* d_in, const int* in_sizes, int n_in,
                              void* d_out, int out_size, void* d_ws, size_t ws_size,
                              hipStream_t stream) {
    const int*   nodes       = (const int*)d_in[0];
    const int*   edges       = (const int*)d_in[1];
    const float* features    = (const float*)d_in[2];
    const float* node_emb    = (const float*)d_in[3];
    const float* feat_W      = (const float*)d_in[4];
    const float* feat_b      = (const float*)d_in[5];
    const float* conv1_W     = (const float*)d_in[6];
    const float* conv1_b     = (const float*)d_in[7];
    const float* pattern_emb = (const float*)d_in[8];
    const int*   pattern_id  = (const int*)d_in[9];
    float* out = (float*)d_out;

    const size_t emb_f32_bytes = (size_t)N_NODES * D * sizeof(float);   // 25.6 MB
    const size_t emb_bf_bytes  = (size_t)N_NODES * D * 2;               // 12.8 MB
    auto align256 = [](size_t x) { return (x + 255) & ~(size_t)255; };

    size_t o_embA = 0;
    size_t o_embB = o_embA + align256(emb_bf_bytes);
    size_t o_xbuf = o_embB + align256(emb_bf_bytes);
    size_t o_col  = o_xbuf + align256(emb_f32_bytes);
    size_t o_rank = o_col  + align256((size_t)N_EDGES * 4);
    size_t o_row  = o_rank + align256((size_t)N_EDGES * 4);
    size_t o_deg  = o_row  + align256((size_t)(N_NODES + 1) * 4);
    size_t o_bsum = o_deg  + align256((size_t)N_NODES * 4);
    size_t o_boff = o_bsum + align256((size_t)NB1 * 4);
    size_t need   = o_boff + align256((size_t)NB1 * 4);

    char* ws = (char*)d_ws;

    if (ws_size >= need) {
        unsigned short* embA = (unsigned short*)(ws + o_embA);
        unsigned short* embB = (unsigned short*)(ws + o_embB);
        float* xbuf = (float*)(ws + o_xbuf);
        int*   col  = (int*)(ws + o_col);
        int*   rank = (int*)(ws + o_rank);
        int*   rowp = (int*)(ws + o_row);
        int*   deg  = (int*)(ws + o_deg);
        int*   bsum = (int*)(ws + o_bsum);
        int*   boff = (int*)(ws + o_boff);

        hipMemsetAsync(deg, 0, (size_t)N_NODES * 4, stream);
        hist_rank_kernel<<<FILL_BLOCKS, 256, 0, stream>>>((const int2*)edges, deg, rank);
        scan1_kernel<<<NB1, SCAN_B, 0, stream>>>(deg, rowp, bsum);
        scan2_kernel<<<1, 512, 0, stream>>>(bsum, boff);
        scan3_kernel<<<NB1, SCAN_B, 0, stream>>>(rowp, boff);
        fill_init_kernel<<<FILL_BLOCKS + INIT_BLOCKS, 256, 0, stream>>>(
            (const int2*)edges, rank, rowp, col,
            nodes, features, node_emb, feat_W, feat_b, embA);

        const int conv_grid = (N_NODES + CT - 1) / CT;   // 1563

        // iter 1: gather(bf16->fp32) + tiled conv -> embB (bf16)
        gather_x_kernel<<<N_NODES / 4, 256, 0, stream>>>(embA, rowp, col, xbuf);
        conv_tile_kernel<false><<<conv_grid, 256, 0, stream>>>(
            xbuf, conv1_W, conv1_b, pattern_emb, pattern_id, embB, nullptr);
        // iter 2: gather + tiled conv fused with cosine score -> out
        gather_x_kernel<<<N_NODES / 4, 256, 0, stream>>>(embB, rowp, col, xbuf);
        conv_tile_kernel<true><<<conv_grid, 256, 0, stream>>>(
            xbuf, conv1_W, conv1_b, pattern_emb, pattern_id, nullptr, out);
    } else {
        float* embeds = (float*)ws;
        float* agg = (float*)(ws + align256(emb_f32_bytes));
        init_embeds_kernel<<<(N_NODES * D + 255) / 256, 256, 0, stream>>>(
            nodes, features, node_emb, feat_W, feat_b, embeds);
        for (int it = 0; it < 2; ++it) {
            hipMemsetAsync(agg, 0, emb_f32_bytes, stream);
            long long total = (long long)N_EDGES * 64;
            scatter_add_kernel<<<(int)((total + 255) / 256), 256, 0, stream>>>(edges, embeds, agg);
            conv_inplace_kernel<<<2048, 256, 0, stream>>>(agg, conv1_W, conv1_b, embeds);
        }
        final_score_kernel<<<(N_NODES + 3) / 4, 256, 0, stream>>>(
            embeds, pattern_emb, pattern_id, out);
    }
}